// Round 15
// baseline (240.850 us; speedup 1.0000x reference)
//
#include <hip/hip_runtime.h>

#define B_ 8
#define N_ 4096
#define O_ 64
#define KL 40
#define KS 20
#define EPSV 1e-5
#define SLOPE 0.2f

typedef unsigned long long u64;
typedef unsigned int u32;

__device__ __forceinline__ float leaky(float v) { return v >= 0.f ? v : SLOPE * v; }

// monotone float<->u32 maps (ascending float == ascending u32)
__device__ __forceinline__ u32 mfloat(float x) {
    const u32 u = __float_as_uint(x);
    return (u & 0x80000000u) ? ~u : (u | 0x80000000u);
}
__device__ __forceinline__ float unmfloat(u32 m) {
    return __uint_as_float((m & 0x80000000u) ? (m ^ 0x80000000u) : ~m);
}

// lane exchange by XOR stride S. S=1,2,8 via DPP (VALU, no LDS); S=4,16,32,63 via
// ds_bpermute with a HOISTED per-lane address.
template <int S>
__device__ __forceinline__ u64 xor_ex64(u64 v, int dsaddr) {
    if constexpr (S == 1 || S == 2 || S == 8) {
        constexpr int CTRL = (S == 1) ? 0xB1 : (S == 2) ? 0x4E : 0x128;
        const int lo = __builtin_amdgcn_update_dpp(0, (int)(u32)v, CTRL, 0xF, 0xF, true);
        const int hi = __builtin_amdgcn_update_dpp(0, (int)(u32)(v >> 32), CTRL, 0xF, 0xF, true);
        return ((u64)(u32)hi << 32) | (u32)lo;
    } else {
        const int lo = __builtin_amdgcn_ds_bpermute(dsaddr, (int)(u32)v);
        const int hi = __builtin_amdgcn_ds_bpermute(dsaddr, (int)(u32)(v >> 32));
        return ((u64)(u32)hi << 32) | (u32)lo;
    }
}

// one bitonic stage (level K, stride S) on four independent key sets (ILP x4)
template <int K, int S>
__device__ __forceinline__ void stage_quad(u64& a, u64& e, u64& f, u64& g,
                                           int lane, int dsaddr) {
    const u64 oa = xor_ex64<S>(a, dsaddr);
    const u64 oe = xor_ex64<S>(e, dsaddr);
    const u64 of = xor_ex64<S>(f, dsaddr);
    const u64 og = xor_ex64<S>(g, dsaddr);
    const bool sel = (((lane & K) == 0) == ((lane & S) == 0));
    a = ((a < oa) == sel) ? a : oa;
    e = ((e < oe) == sel) ? e : oe;
    f = ((f < of) == sel) ? f : of;
    g = ((g < og) == sel) ? g : og;
}

// quad ascending bitonic sort of four independent 64-key sets
__device__ __forceinline__ void sort64_quad(u64& a, u64& e, u64& f, u64& g, int lane,
                                            int a4, int a16, int a32) {
    stage_quad<2, 1>(a, e, f, g, lane, 0);
    stage_quad<4, 2>(a, e, f, g, lane, 0);    stage_quad<4, 1>(a, e, f, g, lane, 0);
    stage_quad<8, 4>(a, e, f, g, lane, a4);   stage_quad<8, 2>(a, e, f, g, lane, 0);    stage_quad<8, 1>(a, e, f, g, lane, 0);
    stage_quad<16, 8>(a, e, f, g, lane, 0);   stage_quad<16, 4>(a, e, f, g, lane, a4);  stage_quad<16, 2>(a, e, f, g, lane, 0);   stage_quad<16, 1>(a, e, f, g, lane, 0);
    stage_quad<32, 16>(a, e, f, g, lane, a16); stage_quad<32, 8>(a, e, f, g, lane, 0);  stage_quad<32, 4>(a, e, f, g, lane, a4);  stage_quad<32, 2>(a, e, f, g, lane, 0);  stage_quad<32, 1>(a, e, f, g, lane, 0);
    stage_quad<64, 32>(a, e, f, g, lane, a32); stage_quad<64, 16>(a, e, f, g, lane, a16); stage_quad<64, 8>(a, e, f, g, lane, 0); stage_quad<64, 4>(a, e, f, g, lane, a4); stage_quad<64, 2>(a, e, f, g, lane, 0); stage_quad<64, 1>(a, e, f, g, lane, 0);
}

// L0..L3 ascending lists; a..g ascending buffers. keep 64 smallest of each union.
__device__ __forceinline__ void merge_quad(u64& L0, u64& L1, u64& L2, u64& L3,
                                           u64 a, u64 e, u64 f, u64 g, int lane,
                                           int a4, int a16, int a32, int a63) {
    const u64 ra = xor_ex64<63>(a, a63);         // reverse -> descending
    const u64 re = xor_ex64<63>(e, a63);
    const u64 rf = xor_ex64<63>(f, a63);
    const u64 rg = xor_ex64<63>(g, a63);
    L0 = (L0 < ra) ? L0 : ra;                    // valley min -> bitonic
    L1 = (L1 < re) ? L1 : re;
    L2 = (L2 < rf) ? L2 : rf;
    L3 = (L3 < rg) ? L3 : rg;
    stage_quad<0, 32>(L0, L1, L2, L3, lane, a32);
    stage_quad<0, 16>(L0, L1, L2, L3, lane, a16);
    stage_quad<0, 8>(L0, L1, L2, L3, lane, 0);
    stage_quad<0, 4>(L0, L1, L2, L3, lane, a4);
    stage_quad<0, 2>(L0, L1, L2, L3, lane, 0);
    stage_quad<0, 1>(L0, L1, L2, L3, lane, 0);
}

// ---------------- K0: bucket points by x -> packed array, envelopes, orig coords -
__global__ __launch_bounds__(1024) void bucket_kernel(const float* __restrict__ x,
                                                      float4* __restrict__ sxp,
                                                      int* __restrict__ perm,
                                                      float2* __restrict__ cb,
                                                      float4* __restrict__ xo4) {
    __shared__ int hist[256];
    __shared__ int scan[256];
    __shared__ int ofs[256];
    __shared__ u32 xsm[4096];
    __shared__ float redmin[16], redmax[16];
    __shared__ u32 wmin[64], wmax[64];
    const int b = blockIdx.x;
    const float* xb = x + (size_t)b * 3 * N_;
    const int t = threadIdx.x;
    float xv[4];
    float mn = INFINITY, mx = -INFINITY;
#pragma unroll
    for (int p = 0; p < 4; ++p) {
        xv[p] = xb[t + p * 1024];
        mn = fminf(mn, xv[p]); mx = fmaxf(mx, xv[p]);
    }
#pragma unroll
    for (int s = 1; s < 64; s <<= 1) {
        mn = fminf(mn, __shfl_xor(mn, s));
        mx = fmaxf(mx, __shfl_xor(mx, s));
    }
    if ((t & 63) == 0) { redmin[t >> 6] = mn; redmax[t >> 6] = mx; }
    if (t < 256) hist[t] = 0;
    __syncthreads();
    if (t == 0) {
        float m0 = INFINITY, m1 = -INFINITY;
        for (int w = 0; w < 16; ++w) { m0 = fminf(m0, redmin[w]); m1 = fmaxf(m1, redmax[w]); }
        redmin[0] = m0; redmax[0] = m1;
    }
    __syncthreads();
    const float xmin = redmin[0];
    const float scale = 256.0f / fmaxf(redmax[0] - xmin, 1e-20f);
    int bk[4];
#pragma unroll
    for (int p = 0; p < 4; ++p) {
        bk[p] = min(255, max(0, (int)((xv[p] - xmin) * scale)));
        atomicAdd(&hist[bk[p]], 1);
    }
    __syncthreads();
    if (t < 256) scan[t] = hist[t];
    __syncthreads();
#pragma unroll
    for (int s = 1; s < 256; s <<= 1) {
        int v = 0;
        if (t < 256 && t >= s) v = scan[t - s];
        __syncthreads();
        if (t < 256) scan[t] += v;
        __syncthreads();
    }
    if (t < 256) ofs[t] = scan[t] - hist[t];
    if (t < 64) { wmin[t] = 0xFFFFFFFFu; wmax[t] = 0; }
    __syncthreads();
#pragma unroll
    for (int p = 0; p < 4; ++p) {
        const int i = t + p * 1024;
        const int dst = atomicAdd(&ofs[bk[p]], 1);
        const float cx = xv[p], cy = xb[N_ + i], cz = xb[2 * N_ + i];
        sxp[((size_t)b << 12) + dst] = make_float4(2.f * cx, 2.f * cy, 2.f * cz,
                                                   -(cx * cx + cy * cy + cz * cz));
        perm[(b << 12) + dst] = i;
        xo4[((size_t)b << 12) + i] = make_float4(cx, cy, cz, 0.f);
        xsm[dst] = mfloat(cx);
    }
    __syncthreads();
#pragma unroll
    for (int p = 0; p < 4; ++p) {
        const int pos = t + p * 1024;
        const int w = pos >> 6;
        atomicMin(&wmin[w], xsm[pos]);
        atomicMax(&wmax[w], xsm[pos]);
    }
    __syncthreads();
    if (t == 0) {
        u32 sm = 0xFFFFFFFFu;
        for (int w = 63; w >= 0; --w) { sm = min(sm, wmin[w]); wmin[w] = sm; }
        u32 pm2 = 0;
        for (int w = 0; w < 64; ++w) { pm2 = max(pm2, wmax[w]); wmax[w] = pm2; }
    }
    __syncthreads();
    if (t < 64) cb[(b << 6) + t] = make_float2(unmfloat(wmin[t]), unmfloat(wmax[t]));
}

// ---------------- K1: KNN (4 queries/wave, home-init + pruned spiral) + stats ----
__global__ __launch_bounds__(256, 7) void knn_kernel(const float4* __restrict__ sxp,
                                                     const int* __restrict__ perm,
                                                     const float2* __restrict__ cb,
                                                     const float4* __restrict__ xo4,
                                                     const float* __restrict__ w_s,
                                                     const float* __restrict__ w_l,
                                                     float* __restrict__ max_s,
                                                     float* __restrict__ min_s,
                                                     float* __restrict__ max_l,
                                                     float* __restrict__ min_l,
                                                     float* __restrict__ qstats) {
    __shared__ u64 buf[4][4][128];      // 16 KB candidate buffers (4 q/wave)
    __shared__ float2 cbl[64];
    __shared__ float sred[4][4][64];    // 4 KB stat partials
    const int sbid = ((blockIdx.x & 7) << 8) | (blockIdx.x >> 3);  // 1 batch/XCD
    const int b = sbid >> 8;
    const int qbase = (sbid & 255) << 4;     // 16 sorted-position queries per block
    const int tid = threadIdx.x;
    const int wave = tid >> 6, lane = tid & 63;
    if (tid < 64) cbl[tid] = cb[(b << 6) + tid];
    const int a4 = (lane ^ 4) << 2, a16 = (lane ^ 16) << 2;
    const int a32 = (lane ^ 32) << 2, a63 = (lane ^ 63) << 2;
    const float4* sp = sxp + ((size_t)b << 12);
    const int* pm = perm + (b << 12);
    const float4* xo = xo4 + ((size_t)b << 12);
    const int i0 = qbase + wave * 4;
    const float4 p0 = sp[i0], p1 = sp[i0 + 1], p2 = sp[i0 + 2], p3 = sp[i0 + 3];
    const float qx0 = 0.5f * p0.x, qy0 = 0.5f * p0.y, qz0 = 0.5f * p0.z, nw0 = p0.w;
    const float qx1 = 0.5f * p1.x, qy1 = 0.5f * p1.y, qz1 = 0.5f * p1.z, nw1 = p1.w;
    const float qx2 = 0.5f * p2.x, qy2 = 0.5f * p2.y, qz2 = 0.5f * p2.z, nw2 = p2.w;
    const float qx3 = 0.5f * p3.x, qy3 = 0.5f * p3.y, qz3 = 0.5f * p3.z, nw3 = p3.w;
    const float qxmin = fminf(fminf(qx0, qx1), fminf(qx2, qx3));
    const float qxmax = fmaxf(fmaxf(qx0, qx1), fmaxf(qx2, qx3));
    int cnt0 = 0, cnt1 = 0, cnt2 = 0, cnt3 = 0;
    __syncthreads();
    const int home = i0 >> 6;
    // ---- home-window direct-sort init ----
    u64 L0, L1, L2, L3;
    float th0, th1, th2, th3;
    {
        const int js = (home << 6) + lane;
        const float4 ch = sp[js];
        const int pj = pm[js];
        const float d0 = fmaf(qx0, ch.x, fmaf(qy0, ch.y, fmaf(qz0, ch.z, ch.w + nw0)));
        const float d1 = fmaf(qx1, ch.x, fmaf(qy1, ch.y, fmaf(qz1, ch.z, ch.w + nw1)));
        const float d2 = fmaf(qx2, ch.x, fmaf(qy2, ch.y, fmaf(qz2, ch.z, ch.w + nw2)));
        const float d3 = fmaf(qx3, ch.x, fmaf(qy3, ch.y, fmaf(qz3, ch.z, ch.w + nw3)));
        u64 k0 = ((u64)__float_as_uint(fminf(d0, -0.0f)) << 32) | (u32)pj;
        u64 k1 = ((u64)__float_as_uint(fminf(d1, -0.0f)) << 32) | (u32)pj;
        u64 k2 = ((u64)__float_as_uint(fminf(d2, -0.0f)) << 32) | (u32)pj;
        u64 k3 = ((u64)__float_as_uint(fminf(d3, -0.0f)) << 32) | (u32)pj;
        sort64_quad(k0, k1, k2, k3, lane, a4, a16, a32);
        L0 = k0; L1 = k1; L2 = k2; L3 = k3;
        th0 = __uint_as_float((u32)__builtin_amdgcn_readlane((int)(u32)(L0 >> 32), KL - 1));
        th1 = __uint_as_float((u32)__builtin_amdgcn_readlane((int)(u32)(L1 >> 32), KL - 1));
        th2 = __uint_as_float((u32)__builtin_amdgcn_readlane((int)(u32)(L2 >> 32), KL - 1));
        th3 = __uint_as_float((u32)__builtin_amdgcn_readlane((int)(u32)(L3 >> 32), KL - 1));
    }
    // ---- pruned spiral, prefetch pipeline ----
    int cl = home - 1, cr = home + 1;
    bool openL = (cl >= 0), openR = (cr < 64);
    bool takeR = true;
    int c = -1;
    float4 cd = make_float4(0.f, 0.f, 0.f, 0.f);
    int pj = 0;
    for (;;) {           // pick first window
        if (!openL && !openR) break;
        const bool pickR = openR && (takeR || !openL);
        takeR = !pickR;
        const float r2 = -fminf(fminf(th0, th1), fminf(th2, th3));
        if (pickR) {
            const float dx = cbl[cr].x - qxmax;
            if (dx > 0.f && dx * dx > r2) { openR = false; continue; }
            c = cr++; if (cr >= 64) openR = false; break;
        } else {
            const float dx = qxmin - cbl[cl].y;
            if (dx > 0.f && dx * dx > r2) { openL = false; continue; }
            c = cl--; if (cl < 0) openL = false; break;
        }
    }
    if (c >= 0) { cd = sp[(c << 6) + lane]; pj = pm[(c << 6) + lane]; }
    while (c >= 0) {
        int cn = -1;     // pick next window + prefetch
        for (;;) {
            if (!openL && !openR) break;
            const bool pickR = openR && (takeR || !openL);
            takeR = !pickR;
            const float r2 = -fminf(fminf(th0, th1), fminf(th2, th3));
            if (pickR) {
                const float dx = cbl[cr].x - qxmax;
                if (dx > 0.f && dx * dx > r2) { openR = false; continue; }
                cn = cr++; if (cr >= 64) openR = false; break;
            } else {
                const float dx = qxmin - cbl[cl].y;
                if (dx > 0.f && dx * dx > r2) { openL = false; continue; }
                cn = cl--; if (cl < 0) openL = false; break;
            }
        }
        float4 nd = make_float4(0.f, 0.f, 0.f, 0.f);
        int nj = 0;
        if (cn >= 0) { nd = sp[(cn << 6) + lane]; nj = pm[(cn << 6) + lane]; }
        // scan current window (4 queries share the load)
        {
            const float d0 = fmaf(qx0, cd.x, fmaf(qy0, cd.y, fmaf(qz0, cd.z, cd.w + nw0)));
            const float d1 = fmaf(qx1, cd.x, fmaf(qy1, cd.y, fmaf(qz1, cd.z, cd.w + nw1)));
            const float d2 = fmaf(qx2, cd.x, fmaf(qy2, cd.y, fmaf(qz2, cd.z, cd.w + nw2)));
            const float d3 = fmaf(qx3, cd.x, fmaf(qy3, cd.y, fmaf(qz3, cd.z, cd.w + nw3)));
            const u64 m0 = __ballot(d0 >= th0);
            const u64 m1 = __ballot(d1 >= th1);
            const u64 m2 = __ballot(d2 >= th2);
            const u64 m3 = __ballot(d3 >= th3);
            if (m0) {
                const int pos = cnt0 + __builtin_amdgcn_mbcnt_hi(
                    (u32)(m0 >> 32), __builtin_amdgcn_mbcnt_lo((u32)m0, 0));
                if (d0 >= th0) buf[wave][0][pos] =
                    ((u64)__float_as_uint(fminf(d0, -0.0f)) << 32) | (u32)pj;
                cnt0 += __popcll(m0);
            }
            if (m1) {
                const int pos = cnt1 + __builtin_amdgcn_mbcnt_hi(
                    (u32)(m1 >> 32), __builtin_amdgcn_mbcnt_lo((u32)m1, 0));
                if (d1 >= th1) buf[wave][1][pos] =
                    ((u64)__float_as_uint(fminf(d1, -0.0f)) << 32) | (u32)pj;
                cnt1 += __popcll(m1);
            }
            if (m2) {
                const int pos = cnt2 + __builtin_amdgcn_mbcnt_hi(
                    (u32)(m2 >> 32), __builtin_amdgcn_mbcnt_lo((u32)m2, 0));
                if (d2 >= th2) buf[wave][2][pos] =
                    ((u64)__float_as_uint(fminf(d2, -0.0f)) << 32) | (u32)pj;
                cnt2 += __popcll(m2);
            }
            if (m3) {
                const int pos = cnt3 + __builtin_amdgcn_mbcnt_hi(
                    (u32)(m3 >> 32), __builtin_amdgcn_mbcnt_lo((u32)m3, 0));
                if (d3 >= th3) buf[wave][3][pos] =
                    ((u64)__float_as_uint(fminf(d3, -0.0f)) << 32) | (u32)pj;
                cnt3 += __popcll(m3);
            }
            if ((cnt0 | cnt1 | cnt2 | cnt3) >= 64) {   // joint flush, 4-way ILP
                const int t0 = min(cnt0, 64), t1 = min(cnt1, 64);
                const int t2 = min(cnt2, 64), t3 = min(cnt3, 64);
                u64 a = (lane < t0) ? buf[wave][0][cnt0 - t0 + lane] : ~0ull;
                u64 e = (lane < t1) ? buf[wave][1][cnt1 - t1 + lane] : ~0ull;
                u64 f = (lane < t2) ? buf[wave][2][cnt2 - t2 + lane] : ~0ull;
                u64 g = (lane < t3) ? buf[wave][3][cnt3 - t3 + lane] : ~0ull;
                sort64_quad(a, e, f, g, lane, a4, a16, a32);
                merge_quad(L0, L1, L2, L3, a, e, f, g, lane, a4, a16, a32, a63);
                th0 = __uint_as_float((u32)__builtin_amdgcn_readlane((int)(u32)(L0 >> 32), KL - 1));
                th1 = __uint_as_float((u32)__builtin_amdgcn_readlane((int)(u32)(L1 >> 32), KL - 1));
                th2 = __uint_as_float((u32)__builtin_amdgcn_readlane((int)(u32)(L2 >> 32), KL - 1));
                th3 = __uint_as_float((u32)__builtin_amdgcn_readlane((int)(u32)(L3 >> 32), KL - 1));
                cnt0 -= t0; cnt1 -= t1; cnt2 -= t2; cnt3 -= t3;
            }
        }
        c = cn; cd = nd; pj = nj;
    }
    if ((cnt0 | cnt1 | cnt2 | cnt3) > 0) {    // leftovers (< 64 each)
        u64 a = (lane < cnt0) ? buf[wave][0][lane] : ~0ull;
        u64 e = (lane < cnt1) ? buf[wave][1][lane] : ~0ull;
        u64 f = (lane < cnt2) ? buf[wave][2][lane] : ~0ull;
        u64 g = (lane < cnt3) ? buf[wave][3][lane] : ~0ull;
        sort64_quad(a, e, f, g, lane, a4, a16, a32);
        merge_quad(L0, L1, L2, L3, a, e, f, g, lane, a4, a16, a32, a63);
    }
    // ---- fused edge-conv stats epilogue (sbuf overlays buf: wave-private) -------
    float4* sbufw = reinterpret_cast<float4*>(&buf[wave][0][0]);   // 4096 B region
    if (lane < KL) {
        sbufw[0 * KL + lane] = xo[(int)((u32)L0 & 4095u)];
        sbufw[1 * KL + lane] = xo[(int)((u32)L1 & 4095u)];
        sbufw[2 * KL + lane] = xo[(int)((u32)L2 & 4095u)];
        sbufw[3 * KL + lane] = xo[(int)((u32)L3 & 4095u)];
    }
    __builtin_amdgcn_wave_barrier();     // per-wave LDS RAW; DS pipe is in-order
    const int lw = lane * 6;             // lane = output channel
    const float ws0 = w_s[lw], ws1 = w_s[lw + 1], ws2 = w_s[lw + 2];
    const float ds0 = w_s[lw + 3] - ws0, ds1 = w_s[lw + 4] - ws1, ds2 = w_s[lw + 5] - ws2;
    const float wl0 = w_l[lw], wl1 = w_l[lw + 1], wl2 = w_l[lw + 2];
    const float dl0 = w_l[lw + 3] - wl0, dl1 = w_l[lw + 4] - wl1, dl2 = w_l[lw + 5] - wl2;
    float st[4] = {0.f, 0.f, 0.f, 0.f};  // sums, sss, suml, ssl over 4 queries
#pragma unroll
    for (int q = 0; q < 4; ++q) {
        const float qx = (q == 0) ? qx0 : (q == 1) ? qx1 : (q == 2) ? qx2 : qx3;
        const float qy = (q == 0) ? qy0 : (q == 1) ? qy1 : (q == 2) ? qy2 : qy3;
        const float qz = (q == 0) ? qz0 : (q == 1) ? qz1 : (q == 2) ? qz2 : qz3;
        const int oi = pm[i0 + q];
        const float cs = fmaf(ds0, qx, fmaf(ds1, qy, ds2 * qz));
        const float cq = fmaf(dl0, qx, fmaf(dl1, qy, dl2 * qz));
        float mxs = -INFINITY, mns = INFINITY, mxl = -INFINITY, mnl = INFINITY;
        float sums = 0.f, sss = 0.f, suml = 0.f, ssl = 0.f;
#pragma unroll
        for (int k = 0; k < KL; ++k) {
            const float4 xj = sbufw[q * KL + k];         // LDS broadcast
            const float hl = fmaf(wl0, xj.x, fmaf(wl1, xj.y, fmaf(wl2, xj.z, cq)));
            mxl = fmaxf(mxl, hl); mnl = fminf(mnl, hl);
            suml += hl; ssl = fmaf(hl, hl, ssl);
            if (k < KS) {
                const float hs = fmaf(ws0, xj.x, fmaf(ws1, xj.y, fmaf(ws2, xj.z, cs)));
                mxs = fmaxf(mxs, hs); mns = fminf(mns, hs);
                sums += hs; sss = fmaf(hs, hs, sss);
            }
        }
        const size_t base = (size_t)((b << 12) + oi) * 64 + lane;
        max_s[base] = mxs; min_s[base] = mns;
        max_l[base] = mxl; min_l[base] = mnl;
        st[0] += sums; st[1] += sss; st[2] += suml; st[3] += ssl;
    }
#pragma unroll
    for (int s = 0; s < 4; ++s) sred[wave][s][lane] = st[s];
    __syncthreads();
    if (tid < 256) {
        const int s = tid >> 6, ch = tid & 63;
        qstats[(size_t)blockIdx.x * 256 + tid] =
            sred[0][s][ch] + sred[1][s][ch] + sred[2][s][ch] + sred[3][s][ch];
    }
}

// ---------------- K4a/K4b: reduce edge-conv BN stats -> scale/bias ---------------
__global__ void reduce1a_kernel(const float* __restrict__ qstats, double* __restrict__ partialD1) {
    const int t = threadIdx.x;   // 256, 32 blocks, 2048 rows total
    double acc = 0.0;
    const int r0 = blockIdx.x * 64;
    for (int r = 0; r < 64; ++r) acc += (double)qstats[(size_t)(r0 + r) * 256 + t];
    partialD1[(size_t)blockIdx.x * 256 + t] = acc;
}

__global__ void reduce1b_kernel(const double* __restrict__ partialD1,
                                const float* __restrict__ g_s, const float* __restrict__ b_s,
                                const float* __restrict__ g_l, const float* __restrict__ b_l,
                                float* __restrict__ sb1) {
    const int t = threadIdx.x;   // 256
    double acc = 0.0;
    for (int r = 0; r < 32; ++r) acc += partialD1[(size_t)r * 256 + t];
    __shared__ double sums[256];
    sums[t] = acc;
    __syncthreads();
    if (t < 64) {
        const double ns = (double)B_ * N_ * KS;
        const double nl = (double)B_ * N_ * KL;
        double mu = sums[t] / ns;
        double var = sums[64 + t] / ns - mu * mu;
        double sc = (double)g_s[t] / sqrt(var + EPSV);
        sb1[t] = (float)sc;
        sb1[64 + t] = (float)((double)b_s[t] - mu * sc);
        mu = sums[128 + t] / nl;
        var = sums[192 + t] / nl - mu * mu;
        sc = (double)g_l[t] / sqrt(var + EPSV);
        sb1[128 + t] = (float)sc;
        sb1[192 + t] = (float)((double)b_l[t] - mu * sc);
    }
}

// ---------------- K5: BN+leaky on maxes, 64x128 fuse matvec, stats ---------------
__global__ __launch_bounds__(256) void fuse_kernel(
    const float* __restrict__ max_s, const float* __restrict__ min_s,
    const float* __restrict__ max_l, const float* __restrict__ min_l,
    const float* __restrict__ sb1, const float* __restrict__ w_f,
    float* __restrict__ f_buf, float* __restrict__ partial2) {
    __shared__ float wfT[128 * 64];   // transposed: wfT[c][o]
    __shared__ float av[4][128];
    __shared__ float red[2][4][64];
    const int tid = threadIdx.x;
    for (int t = tid; t < 8192; t += 256) {
        const int c = t >> 6, o = t & 63;
        wfT[t] = w_f[o * 128 + c];
    }
    const int sbid = ((blockIdx.x & 7) << 8) + (blockIdx.x >> 3);   // 1 batch/XCD
    const int wave = tid >> 6, lane = tid & 63;
    const float sc_s = sb1[lane], bi_s = sb1[64 + lane];
    const float sc_l = sb1[128 + lane], bi_l = sb1[192 + lane];
    float sum_f = 0.f, ss_f = 0.f;
    __syncthreads();
    for (int p = 0; p < 4; ++p) {
        const int bn = (sbid * 4 + wave) * 4 + p;   // 2048 blocks
        const size_t base = (size_t)bn * 64 + lane;
        const float hs = sc_s >= 0.f ? max_s[base] : min_s[base];
        const float a_s = leaky(fmaf(sc_s, hs, bi_s));
        const float hl = sc_l >= 0.f ? max_l[base] : min_l[base];
        const float a_l = leaky(fmaf(sc_l, hl, bi_l));
        av[wave][lane] = a_s;
        av[wave][64 + lane] = a_l;     // per-wave buffer: no block barrier needed
        float acc = 0.f;
#pragma unroll
        for (int c = 0; c < 128; ++c) acc = fmaf(wfT[c * 64 + lane], av[wave][c], acc);
        f_buf[base] = acc;
        sum_f += acc;
        ss_f = fmaf(acc, acc, ss_f);
    }
    red[0][wave][lane] = sum_f;
    red[1][wave][lane] = ss_f;
    __syncthreads();
    if (tid < 128) {
        const int st = tid >> 6, o = tid & 63;
        partial2[(size_t)blockIdx.x * 128 + tid] =
            red[st][0][o] + red[st][1][o] + red[st][2][o] + red[st][3][o];
    }
}

// ---------------- K6a/K6b: reduce final BN stats ---------------------------------
__global__ void reduce2a_kernel(const float* __restrict__ partial2, double* __restrict__ partialD2) {
    const int t = threadIdx.x;   // 128
    double acc = 0.0;
    const int r0 = blockIdx.x * 32;   // 64 blocks
    for (int r = 0; r < 32; ++r) acc += (double)partial2[(size_t)(r0 + r) * 128 + t];
    partialD2[(size_t)blockIdx.x * 128 + t] = acc;
}

__global__ void reduce2b_kernel(const double* __restrict__ partialD2,
                                const float* __restrict__ g_f, const float* __restrict__ b_f,
                                float* __restrict__ sb2) {
    const int t = threadIdx.x;   // 128
    double acc = 0.0;
    for (int r = 0; r < 64; ++r) acc += partialD2[(size_t)r * 128 + t];
    __shared__ double sums[128];
    sums[t] = acc;
    __syncthreads();
    if (t < 64) {
        const double n = (double)B_ * N_;
        const double mu = sums[t] / n;
        const double var = sums[64 + t] / n - mu * mu;
        const double sc = (double)g_f[t] / sqrt(var + EPSV);
        sb2[t] = (float)sc;
        sb2[64 + t] = (float)((double)b_f[t] - mu * sc);
    }
}

// ---------------- K7: final BN+leaky + transpose to [B,O,N] ----------------------
__global__ __launch_bounds__(256) void final_kernel(const float* __restrict__ f_buf,
                                                    const float* __restrict__ sb2,
                                                    float* __restrict__ out) {
    __shared__ float tile[64][65];
    const int sbid = ((blockIdx.x & 7) << 6) + (blockIdx.x >> 3);   // 1 batch/XCD
    const int b = sbid >> 6;                 // 512 blocks
    const int n0 = (sbid & 63) << 6;
#pragma unroll
    for (int r = 0; r < 16; ++r) {
        const int t = r * 256 + threadIdx.x;
        const int n = t >> 6, o = t & 63;
        const float v = f_buf[(size_t)((b << 12) + n0 + n) * 64 + o];
        const float h = fmaf(sb2[o], v, sb2[64 + o]);
        tile[n][o] = leaky(h);
    }
    __syncthreads();
#pragma unroll
    for (int r = 0; r < 16; ++r) {
        const int t = r * 256 + threadIdx.x;
        const int o = t >> 6, n = t & 63;
        out[(size_t)((b << 6) + o) * N_ + n0 + n] = tile[n][o];
    }
}

// ---------------- launch ---------------------------------------------------------
extern "C" void kernel_launch(void* const* d_in, const int* in_sizes, int n_in,
                              void* d_out, int out_size, void* d_ws, size_t ws_size,
                              hipStream_t stream) {
    (void)in_sizes; (void)n_in; (void)out_size; (void)ws_size;
    const float* x   = (const float*)d_in[0];
    const float* w_s = (const float*)d_in[1];
    const float* g_s = (const float*)d_in[2];
    const float* b_s = (const float*)d_in[3];
    const float* w_l = (const float*)d_in[4];
    const float* g_l = (const float*)d_in[5];
    const float* b_l = (const float*)d_in[6];
    const float* w_f = (const float*)d_in[7];
    const float* g_f = (const float*)d_in[8];
    const float* b_f = (const float*)d_in[9];
    float* out = (float*)d_out;
    char* ws = (char*)d_ws;

    constexpr size_t SZ_PT   = (size_t)B_ * N_ * 64 * 4;            // 8 MB
    constexpr size_t OFF_MXS = 0;
    constexpr size_t OFF_MNS = OFF_MXS + SZ_PT;
    constexpr size_t OFF_MXL = OFF_MNS + SZ_PT;
    constexpr size_t OFF_MNL = OFF_MXL + SZ_PT;
    constexpr size_t OFF_QST = OFF_MNL + SZ_PT;                     // 2 MB
    constexpr size_t OFF_PD1 = OFF_QST + (size_t)2048 * 256 * 4;
    constexpr size_t OFF_SB1 = OFF_PD1 + (size_t)32 * 256 * 8;
    constexpr size_t OFF_F   = OFF_SB1 + 1024;
    constexpr size_t OFF_P2  = OFF_F + SZ_PT;
    constexpr size_t OFF_PD2 = OFF_P2 + (size_t)2048 * 128 * 4;
    constexpr size_t OFF_SB2 = OFF_PD2 + (size_t)64 * 128 * 8;
    constexpr size_t OFF_SXP = OFF_SB2 + 1024;                      // 512 KB
    constexpr size_t OFF_PRM = OFF_SXP + (size_t)B_ * N_ * 16;      // 128 KB
    constexpr size_t OFF_CB  = OFF_PRM + (size_t)B_ * N_ * 4;       // 4 KB
    constexpr size_t OFF_XO4 = OFF_CB + (size_t)B_ * 64 * 8;        // 512 KB

    float*  mxs  = (float*)(ws + OFF_MXS);
    float*  mns  = (float*)(ws + OFF_MNS);
    float*  mxl  = (float*)(ws + OFF_MXL);
    float*  mnl  = (float*)(ws + OFF_MNL);
    float*  qst  = (float*)(ws + OFF_QST);
    double* pd1  = (double*)(ws + OFF_PD1);
    float*  sb1  = (float*)(ws + OFF_SB1);
    float*  fb   = (float*)(ws + OFF_F);
    float*  p2   = (float*)(ws + OFF_P2);
    double* pd2  = (double*)(ws + OFF_PD2);
    float*  sb2  = (float*)(ws + OFF_SB2);
    float4* sxp  = (float4*)(ws + OFF_SXP);
    int*    prm  = (int*)(ws + OFF_PRM);
    float2* cbv  = (float2*)(ws + OFF_CB);
    float4* xo4  = (float4*)(ws + OFF_XO4);

    hipLaunchKernelGGL(bucket_kernel, dim3(8), dim3(1024), 0, stream, x, sxp, prm, cbv, xo4);
    hipLaunchKernelGGL(knn_kernel, dim3(2048), dim3(256), 0, stream,
                       sxp, prm, cbv, xo4, w_s, w_l, mxs, mns, mxl, mnl, qst);
    hipLaunchKernelGGL(reduce1a_kernel, dim3(32), dim3(256), 0, stream, qst, pd1);
    hipLaunchKernelGGL(reduce1b_kernel, dim3(1), dim3(256), 0, stream, pd1, g_s, b_s, g_l, b_l, sb1);
    hipLaunchKernelGGL(fuse_kernel, dim3(2048), dim3(256), 0, stream,
                       mxs, mns, mxl, mnl, sb1, w_f, fb, p2);
    hipLaunchKernelGGL(reduce2a_kernel, dim3(64), dim3(128), 0, stream, p2, pd2);
    hipLaunchKernelGGL(reduce2b_kernel, dim3(1), dim3(128), 0, stream, pd2, g_f, b_f, sb2);
    hipLaunchKernelGGL(final_kernel, dim3(512), dim3(256), 0, stream, fb, sb2, out);
}

// Round 16
// 202.641 us; speedup vs baseline: 1.1886x; 1.1886x over previous
//
#include <hip/hip_runtime.h>

#define B_ 8
#define N_ 4096
#define O_ 64
#define KL 40
#define KS 20
#define EPSV 1e-5
#define SLOPE 0.2f

typedef unsigned long long u64;
typedef unsigned int u32;

__device__ __forceinline__ float leaky(float v) { return v >= 0.f ? v : SLOPE * v; }

// monotone float<->u32 maps (ascending float == ascending u32)
__device__ __forceinline__ u32 mfloat(float x) {
    const u32 u = __float_as_uint(x);
    return (u & 0x80000000u) ? ~u : (u | 0x80000000u);
}
__device__ __forceinline__ float unmfloat(u32 m) {
    return __uint_as_float((m & 0x80000000u) ? (m ^ 0x80000000u) : ~m);
}

// lane exchange by XOR stride S. S=1,2,8 via DPP (VALU, no LDS); S=4,16,32,63 via
// ds_bpermute with a HOISTED per-lane address.
template <int S>
__device__ __forceinline__ u64 xor_ex64(u64 v, int dsaddr) {
    if constexpr (S == 1 || S == 2 || S == 8) {
        constexpr int CTRL = (S == 1) ? 0xB1 : (S == 2) ? 0x4E : 0x128;
        const int lo = __builtin_amdgcn_update_dpp(0, (int)(u32)v, CTRL, 0xF, 0xF, true);
        const int hi = __builtin_amdgcn_update_dpp(0, (int)(u32)(v >> 32), CTRL, 0xF, 0xF, true);
        return ((u64)(u32)hi << 32) | (u32)lo;
    } else {
        const int lo = __builtin_amdgcn_ds_bpermute(dsaddr, (int)(u32)v);
        const int hi = __builtin_amdgcn_ds_bpermute(dsaddr, (int)(u32)(v >> 32));
        return ((u64)(u32)hi << 32) | (u32)lo;
    }
}

// one bitonic stage (level K, stride S) applied to two independent keys (ILP x2)
template <int K, int S>
__device__ __forceinline__ void stage_pair(u64& a, u64& e, int lane, int dsaddr) {
    const u64 oa = xor_ex64<S>(a, dsaddr);
    const u64 oe = xor_ex64<S>(e, dsaddr);
    const bool sel = (((lane & K) == 0) == ((lane & S) == 0));
    a = ((a < oa) == sel) ? a : oa;
    e = ((e < oe) == sel) ? e : oe;
}

// dual ascending bitonic sort of two independent 64-key sets
__device__ __forceinline__ void sort64_pair(u64& a, u64& e, int lane,
                                            int a4, int a16, int a32) {
    stage_pair<2, 1>(a, e, lane, 0);
    stage_pair<4, 2>(a, e, lane, 0);    stage_pair<4, 1>(a, e, lane, 0);
    stage_pair<8, 4>(a, e, lane, a4);   stage_pair<8, 2>(a, e, lane, 0);    stage_pair<8, 1>(a, e, lane, 0);
    stage_pair<16, 8>(a, e, lane, 0);   stage_pair<16, 4>(a, e, lane, a4);  stage_pair<16, 2>(a, e, lane, 0);   stage_pair<16, 1>(a, e, lane, 0);
    stage_pair<32, 16>(a, e, lane, a16); stage_pair<32, 8>(a, e, lane, 0);  stage_pair<32, 4>(a, e, lane, a4);  stage_pair<32, 2>(a, e, lane, 0);  stage_pair<32, 1>(a, e, lane, 0);
    stage_pair<64, 32>(a, e, lane, a32); stage_pair<64, 16>(a, e, lane, a16); stage_pair<64, 8>(a, e, lane, 0); stage_pair<64, 4>(a, e, lane, a4); stage_pair<64, 2>(a, e, lane, 0); stage_pair<64, 1>(a, e, lane, 0);
}

// L0/L1 ascending lists; a/e ascending buffers. keep 64 smallest of each union.
__device__ __forceinline__ void merge_pair(u64& L0, u64& L1, u64 a, u64 e, int lane,
                                           int a4, int a16, int a32, int a63) {
    const u64 ra = xor_ex64<63>(a, a63);         // reverse -> descending
    const u64 re = xor_ex64<63>(e, a63);
    L0 = (L0 < ra) ? L0 : ra;                    // valley min -> bitonic
    L1 = (L1 < re) ? L1 : re;
    stage_pair<0, 32>(L0, L1, lane, a32);        // K=0 -> pure descending cleanup
    stage_pair<0, 16>(L0, L1, lane, a16);
    stage_pair<0, 8>(L0, L1, lane, 0);
    stage_pair<0, 4>(L0, L1, lane, a4);
    stage_pair<0, 2>(L0, L1, lane, 0);
    stage_pair<0, 1>(L0, L1, lane, 0);
}

// ---------------- K0: bucket points by x -> packed array, envelopes, orig coords -
__global__ __launch_bounds__(1024) void bucket_kernel(const float* __restrict__ x,
                                                      float4* __restrict__ sxp,
                                                      int* __restrict__ perm,
                                                      float2* __restrict__ cb,
                                                      float4* __restrict__ xo4) {
    __shared__ int hist[256];
    __shared__ int scan[256];
    __shared__ int ofs[256];
    __shared__ u32 xsm[4096];
    __shared__ float redmin[16], redmax[16];
    __shared__ u32 wmin[64], wmax[64];
    __shared__ u32 wsuf[64], wpre[64];
    const int b = blockIdx.x;
    const float* xb = x + (size_t)b * 3 * N_;
    const int t = threadIdx.x;
    float xv[4];
    float mn = INFINITY, mx = -INFINITY;
#pragma unroll
    for (int p = 0; p < 4; ++p) {
        xv[p] = xb[t + p * 1024];
        mn = fminf(mn, xv[p]); mx = fmaxf(mx, xv[p]);
    }
#pragma unroll
    for (int s = 1; s < 64; s <<= 1) {
        mn = fminf(mn, __shfl_xor(mn, s));
        mx = fmaxf(mx, __shfl_xor(mx, s));
    }
    if ((t & 63) == 0) { redmin[t >> 6] = mn; redmax[t >> 6] = mx; }
    if (t < 256) hist[t] = 0;
    __syncthreads();
    if (t == 0) {
        float m0 = INFINITY, m1 = -INFINITY;
        for (int w = 0; w < 16; ++w) { m0 = fminf(m0, redmin[w]); m1 = fmaxf(m1, redmax[w]); }
        redmin[0] = m0; redmax[0] = m1;
    }
    __syncthreads();
    const float xmin = redmin[0];
    const float scale = 256.0f / fmaxf(redmax[0] - xmin, 1e-20f);
    int bk[4];
#pragma unroll
    for (int p = 0; p < 4; ++p) {
        bk[p] = min(255, max(0, (int)((xv[p] - xmin) * scale)));
        atomicAdd(&hist[bk[p]], 1);
    }
    __syncthreads();
    if (t < 256) scan[t] = hist[t];
    __syncthreads();
#pragma unroll
    for (int s = 1; s < 256; s <<= 1) {
        int v = 0;
        if (t < 256 && t >= s) v = scan[t - s];
        __syncthreads();
        if (t < 256) scan[t] += v;
        __syncthreads();
    }
    if (t < 256) ofs[t] = scan[t] - hist[t];
    if (t < 64) { wmin[t] = 0xFFFFFFFFu; wmax[t] = 0; }
    __syncthreads();
#pragma unroll
    for (int p = 0; p < 4; ++p) {
        const int i = t + p * 1024;
        const int dst = atomicAdd(&ofs[bk[p]], 1);
        const float cx = xv[p], cy = xb[N_ + i], cz = xb[2 * N_ + i];
        sxp[((size_t)b << 12) + dst] = make_float4(2.f * cx, 2.f * cy, 2.f * cz,
                                                   -(cx * cx + cy * cy + cz * cz));
        perm[(b << 12) + dst] = i;
        xo4[((size_t)b << 12) + i] = make_float4(cx, cy, cz, 0.f);
        xsm[dst] = mfloat(cx);
    }
    __syncthreads();
#pragma unroll
    for (int p = 0; p < 4; ++p) {
        const int pos = t + p * 1024;
        const int w = pos >> 6;
        atomicMin(&wmin[w], xsm[pos]);
        atomicMax(&wmax[w], xsm[pos]);
    }
    __syncthreads();
    // monotone envelopes in parallel: suffix-min of lows, prefix-max of highs
    if (t < 64) {
        u32 sm = 0xFFFFFFFFu;
        for (int w = t; w < 64; ++w) sm = min(sm, wmin[w]);
        wsuf[t] = sm;
    } else if (t < 128) {
        const int tt = t - 64;
        u32 pm2 = 0;
        for (int w = 0; w <= tt; ++w) pm2 = max(pm2, wmax[w]);
        wpre[tt] = pm2;
    }
    __syncthreads();
    if (t < 64) cb[(b << 6) + t] = make_float2(unmfloat(wsuf[t]), unmfloat(wpre[t]));
}

// ---------------- K1: KNN (home-init + pruned spiral) + fused edge-conv stats ----
__global__ __launch_bounds__(256, 8) void knn_kernel(const float4* __restrict__ sxp,
                                                     const int* __restrict__ perm,
                                                     const float2* __restrict__ cb,
                                                     const float4* __restrict__ xo4,
                                                     const float* __restrict__ w_s,
                                                     const float* __restrict__ w_l,
                                                     float* __restrict__ max_s,
                                                     float* __restrict__ min_s,
                                                     float* __restrict__ max_l,
                                                     float* __restrict__ min_l,
                                                     float* __restrict__ qstats) {
    __shared__ u64 buf[4][2][128];      // 8 KB candidate buffers
    __shared__ float2 cbl[64];          // window x-envelopes
    __shared__ float4 sbuf[4][2][KL];   // 5 KB: per-wave neighbor coords
    __shared__ float sred[4][4][64];    // 4 KB: per-wave stat partials
    const int sbid = ((blockIdx.x & 7) << 9) | (blockIdx.x >> 3);  // 1 batch/XCD
    const int b = sbid >> 9;
    const int qbase = (sbid & 511) << 3;     // 8 sorted-position queries per block
    const int tid = threadIdx.x;
    const int wave = tid >> 6, lane = tid & 63;
    if (tid < 64) cbl[tid] = cb[(b << 6) + tid];
    const int a4 = (lane ^ 4) << 2, a16 = (lane ^ 16) << 2;
    const int a32 = (lane ^ 32) << 2, a63 = (lane ^ 63) << 2;
    const float4* sp = sxp + ((size_t)b << 12);
    const int* pm = perm + (b << 12);
    const float4* xo = xo4 + ((size_t)b << 12);
    const int i0 = qbase + wave * 2;
    const float4 p0 = sp[i0], p1 = sp[i0 + 1];
    const float qx0 = 0.5f * p0.x, qy0 = 0.5f * p0.y, qz0 = 0.5f * p0.z, nw0 = p0.w;
    const float qx1 = 0.5f * p1.x, qy1 = 0.5f * p1.y, qz1 = 0.5f * p1.z, nw1 = p1.w;
    const float qxmin = fminf(qx0, qx1), qxmax = fmaxf(qx0, qx1);
    int cnt0 = 0, cnt1 = 0;
    __syncthreads();
    const int home = i0 >> 6;
    // ---- home-window direct-sort init: list = sorted home candidates ------------
    u64 L0, L1;
    float th0, th1;
    {
        const int js = (home << 6) + lane;
        const float4 ch = sp[js];
        const int pj = pm[js];
        const float d0 = fmaf(qx0, ch.x, fmaf(qy0, ch.y, fmaf(qz0, ch.z, ch.w + nw0)));
        const float d1 = fmaf(qx1, ch.x, fmaf(qy1, ch.y, fmaf(qz1, ch.z, ch.w + nw1)));
        u64 k0 = ((u64)__float_as_uint(fminf(d0, -0.0f)) << 32) | (u32)pj;
        u64 k1 = ((u64)__float_as_uint(fminf(d1, -0.0f)) << 32) | (u32)pj;
        sort64_pair(k0, k1, lane, a4, a16, a32);
        L0 = k0; L1 = k1;
        th0 = __uint_as_float((u32)__builtin_amdgcn_readlane((int)(u32)(L0 >> 32), KL - 1));
        th1 = __uint_as_float((u32)__builtin_amdgcn_readlane((int)(u32)(L1 >> 32), KL - 1));
    }
    // ---- pruned spiral over remaining windows, prefetch pipeline ----------------
    int cl = home - 1, cr = home + 1;
    bool openL = (cl >= 0), openR = (cr < 64);
    bool takeR = true;
    int c = -1;
    float4 cd = make_float4(0.f, 0.f, 0.f, 0.f);
    for (;;) {           // pick first window
        if (!openL && !openR) break;
        const bool pickR = openR && (takeR || !openL);
        takeR = !pickR;
        const float r2 = -fminf(th0, th1);
        if (pickR) {
            const float dx = cbl[cr].x - qxmax;
            if (dx > 0.f && dx * dx > r2) { openR = false; continue; }
            c = cr++; if (cr >= 64) openR = false; break;
        } else {
            const float dx = qxmin - cbl[cl].y;
            if (dx > 0.f && dx * dx > r2) { openL = false; continue; }
            c = cl--; if (cl < 0) openL = false; break;
        }
    }
    if (c >= 0) cd = sp[(c << 6) + lane];
    while (c >= 0) {
        int cn = -1;     // pick next window + prefetch its data
        for (;;) {
            if (!openL && !openR) break;
            const bool pickR = openR && (takeR || !openL);
            takeR = !pickR;
            const float r2 = -fminf(th0, th1);
            if (pickR) {
                const float dx = cbl[cr].x - qxmax;
                if (dx > 0.f && dx * dx > r2) { openR = false; continue; }
                cn = cr++; if (cr >= 64) openR = false; break;
            } else {
                const float dx = qxmin - cbl[cl].y;
                if (dx > 0.f && dx * dx > r2) { openL = false; continue; }
                cn = cl--; if (cl < 0) openL = false; break;
            }
        }
        float4 nd = make_float4(0.f, 0.f, 0.f, 0.f);
        if (cn >= 0) nd = sp[(cn << 6) + lane];
        // scan current window (perm load deferred to accept branch)
        {
            const float d0 = fmaf(qx0, cd.x, fmaf(qy0, cd.y, fmaf(qz0, cd.z, cd.w + nw0)));
            const float d1 = fmaf(qx1, cd.x, fmaf(qy1, cd.y, fmaf(qz1, cd.z, cd.w + nw1)));
            const bool pr0 = (d0 >= th0), pr1 = (d1 >= th1);
            const u64 m0 = __ballot(pr0), m1 = __ballot(pr1);
            int pjv = 0;
            if (pr0 || pr1) pjv = pm[(c << 6) + lane];   // exec-masked scattered load
            if (m0) {
                const int pos = cnt0 + __builtin_amdgcn_mbcnt_hi(
                    (u32)(m0 >> 32), __builtin_amdgcn_mbcnt_lo((u32)m0, 0));
                if (pr0) {
                    const u32 kd = __float_as_uint(fminf(d0, -0.0f));
                    buf[wave][0][pos] = ((u64)kd << 32) | (u32)pjv;
                }
                cnt0 += __popcll(m0);
            }
            if (m1) {
                const int pos = cnt1 + __builtin_amdgcn_mbcnt_hi(
                    (u32)(m1 >> 32), __builtin_amdgcn_mbcnt_lo((u32)m1, 0));
                if (pr1) {
                    const u32 kd = __float_as_uint(fminf(d1, -0.0f));
                    buf[wave][1][pos] = ((u64)kd << 32) | (u32)pjv;
                }
                cnt1 += __popcll(m1);
            }
            if ((cnt0 | cnt1) >= 64) {
                const int t0 = min(cnt0, 64), t1 = min(cnt1, 64);
                u64 a = (lane < t0) ? buf[wave][0][cnt0 - t0 + lane] : ~0ull;
                u64 e = (lane < t1) ? buf[wave][1][cnt1 - t1 + lane] : ~0ull;
                sort64_pair(a, e, lane, a4, a16, a32);
                merge_pair(L0, L1, a, e, lane, a4, a16, a32, a63);
                th0 = __uint_as_float((u32)__builtin_amdgcn_readlane((int)(u32)(L0 >> 32), KL - 1));
                th1 = __uint_as_float((u32)__builtin_amdgcn_readlane((int)(u32)(L1 >> 32), KL - 1));
                cnt0 -= t0; cnt1 -= t1;
            }
        }
        c = cn; cd = nd;
    }
    if ((cnt0 | cnt1) > 0) {                  // leftovers (< 64 each)
        u64 a = (lane < cnt0) ? buf[wave][0][lane] : ~0ull;
        u64 e = (lane < cnt1) ? buf[wave][1][lane] : ~0ull;
        sort64_pair(a, e, lane, a4, a16, a32);
        merge_pair(L0, L1, a, e, lane, a4, a16, a32, a63);
    }
    // ---- fused edge-conv stats epilogue ------------------------------------------
    if (lane < KL) {
        sbuf[wave][0][lane] = xo[(int)((u32)L0 & 4095u)];
        sbuf[wave][1][lane] = xo[(int)((u32)L1 & 4095u)];
    }
    __builtin_amdgcn_wave_barrier();     // per-wave LDS RAW; DS pipe is in-order
    const int lw = lane * 6;             // lane = output channel
    const float ws0 = w_s[lw], ws1 = w_s[lw + 1], ws2 = w_s[lw + 2];
    const float ds0 = w_s[lw + 3] - ws0, ds1 = w_s[lw + 4] - ws1, ds2 = w_s[lw + 5] - ws2;
    const float wl0 = w_l[lw], wl1 = w_l[lw + 1], wl2 = w_l[lw + 2];
    const float dl0 = w_l[lw + 3] - wl0, dl1 = w_l[lw + 4] - wl1, dl2 = w_l[lw + 5] - wl2;
    const int oi0 = pm[i0], oi1 = pm[i0 + 1];
    float st[4] = {0.f, 0.f, 0.f, 0.f};  // sums, sss, suml, ssl (both queries)
#pragma unroll
    for (int q = 0; q < 2; ++q) {
        const float qx = q ? qx1 : qx0, qy = q ? qy1 : qy0, qz = q ? qz1 : qz0;
        const int oi = q ? oi1 : oi0;
        const float cs = fmaf(ds0, qx, fmaf(ds1, qy, ds2 * qz));
        const float cq = fmaf(dl0, qx, fmaf(dl1, qy, dl2 * qz));
        float mxs = -INFINITY, mns = INFINITY, mxl = -INFINITY, mnl = INFINITY;
        float sums = 0.f, sss = 0.f, suml = 0.f, ssl = 0.f;
#pragma unroll
        for (int k = 0; k < KL; ++k) {
            const float4 xj = sbuf[wave][q][k];          // LDS broadcast
            const float hl = fmaf(wl0, xj.x, fmaf(wl1, xj.y, fmaf(wl2, xj.z, cq)));
            mxl = fmaxf(mxl, hl); mnl = fminf(mnl, hl);
            suml += hl; ssl = fmaf(hl, hl, ssl);
            if (k < KS) {
                const float hs = fmaf(ws0, xj.x, fmaf(ws1, xj.y, fmaf(ws2, xj.z, cs)));
                mxs = fmaxf(mxs, hs); mns = fminf(mns, hs);
                sums += hs; sss = fmaf(hs, hs, sss);
            }
        }
        const size_t base = (size_t)((b << 12) + oi) * 64 + lane;
        max_s[base] = mxs; min_s[base] = mns;
        max_l[base] = mxl; min_l[base] = mnl;
        st[0] += sums; st[1] += sss; st[2] += suml; st[3] += ssl;
    }
#pragma unroll
    for (int s = 0; s < 4; ++s) sred[wave][s][lane] = st[s];
    __syncthreads();
    if (tid < 256) {
        const int s = tid >> 6, ch = tid & 63;
        qstats[(size_t)blockIdx.x * 256 + tid] =
            sred[0][s][ch] + sred[1][s][ch] + sred[2][s][ch] + sred[3][s][ch];
    }
}

// ---------------- K4a/K4b: reduce edge-conv BN stats -> scale/bias ---------------
__global__ void reduce1a_kernel(const float* __restrict__ qstats, double* __restrict__ partialD1) {
    const int t = threadIdx.x;   // 256, 32 blocks
    double acc = 0.0;
    const int r0 = blockIdx.x * 128;
    for (int r = 0; r < 128; ++r) acc += (double)qstats[(size_t)(r0 + r) * 256 + t];
    partialD1[(size_t)blockIdx.x * 256 + t] = acc;
}

__global__ void reduce1b_kernel(const double* __restrict__ partialD1,
                                const float* __restrict__ g_s, const float* __restrict__ b_s,
                                const float* __restrict__ g_l, const float* __restrict__ b_l,
                                float* __restrict__ sb1) {
    const int t = threadIdx.x;   // 256
    double acc = 0.0;
    for (int r = 0; r < 32; ++r) acc += partialD1[(size_t)r * 256 + t];
    __shared__ double sums[256];
    sums[t] = acc;
    __syncthreads();
    if (t < 64) {
        const double ns = (double)B_ * N_ * KS;
        const double nl = (double)B_ * N_ * KL;
        double mu = sums[t] / ns;
        double var = sums[64 + t] / ns - mu * mu;
        double sc = (double)g_s[t] / sqrt(var + EPSV);
        sb1[t] = (float)sc;
        sb1[64 + t] = (float)((double)b_s[t] - mu * sc);
        mu = sums[128 + t] / nl;
        var = sums[192 + t] / nl - mu * mu;
        sc = (double)g_l[t] / sqrt(var + EPSV);
        sb1[128 + t] = (float)sc;
        sb1[192 + t] = (float)((double)b_l[t] - mu * sc);
    }
}

// ---------------- K5: BN+leaky on maxes, 64x128 fuse matvec, stats ---------------
__global__ __launch_bounds__(256) void fuse_kernel(
    const float* __restrict__ max_s, const float* __restrict__ min_s,
    const float* __restrict__ max_l, const float* __restrict__ min_l,
    const float* __restrict__ sb1, const float* __restrict__ w_f,
    float* __restrict__ f_buf, float* __restrict__ partial2) {
    __shared__ float wfT[128 * 64];   // transposed: wfT[c][o]
    __shared__ float av[4][128];
    __shared__ float red[2][4][64];
    const int tid = threadIdx.x;
    for (int t = tid; t < 8192; t += 256) {
        const int c = t >> 6, o = t & 63;
        wfT[t] = w_f[o * 128 + c];
    }
    const int sbid = ((blockIdx.x & 7) << 8) + (blockIdx.x >> 3);   // 1 batch/XCD
    const int wave = tid >> 6, lane = tid & 63;
    const float sc_s = sb1[lane], bi_s = sb1[64 + lane];
    const float sc_l = sb1[128 + lane], bi_l = sb1[192 + lane];
    float sum_f = 0.f, ss_f = 0.f;
    __syncthreads();
    for (int p = 0; p < 4; ++p) {
        const int bn = (sbid * 4 + wave) * 4 + p;   // 2048 blocks
        const size_t base = (size_t)bn * 64 + lane;
        const float hs = sc_s >= 0.f ? max_s[base] : min_s[base];
        const float a_s = leaky(fmaf(sc_s, hs, bi_s));
        const float hl = sc_l >= 0.f ? max_l[base] : min_l[base];
        const float a_l = leaky(fmaf(sc_l, hl, bi_l));
        av[wave][lane] = a_s;
        av[wave][64 + lane] = a_l;     // per-wave buffer: no block barrier needed
        float acc = 0.f;
#pragma unroll
        for (int c = 0; c < 128; ++c) acc = fmaf(wfT[c * 64 + lane], av[wave][c], acc);
        f_buf[base] = acc;
        sum_f += acc;
        ss_f = fmaf(acc, acc, ss_f);
    }
    red[0][wave][lane] = sum_f;
    red[1][wave][lane] = ss_f;
    __syncthreads();
    if (tid < 128) {
        const int st = tid >> 6, o = tid & 63;
        partial2[(size_t)blockIdx.x * 128 + tid] =
            red[st][0][o] + red[st][1][o] + red[st][2][o] + red[st][3][o];
    }
}

// ---------------- K6a/K6b: reduce final BN stats ---------------------------------
__global__ void reduce2a_kernel(const float* __restrict__ partial2, double* __restrict__ partialD2) {
    const int t = threadIdx.x;   // 128
    double acc = 0.0;
    const int r0 = blockIdx.x * 32;   // 64 blocks
    for (int r = 0; r < 32; ++r) acc += (double)partial2[(size_t)(r0 + r) * 128 + t];
    partialD2[(size_t)blockIdx.x * 128 + t] = acc;
}

__global__ void reduce2b_kernel(const double* __restrict__ partialD2,
                                const float* __restrict__ g_f, const float* __restrict__ b_f,
                                float* __restrict__ sb2) {
    const int t = threadIdx.x;   // 128
    double acc = 0.0;
    for (int r = 0; r < 64; ++r) acc += partialD2[(size_t)r * 128 + t];
    __shared__ double sums[128];
    sums[t] = acc;
    __syncthreads();
    if (t < 64) {
        const double n = (double)B_ * N_;
        const double mu = sums[t] / n;
        const double var = sums[64 + t] / n - mu * mu;
        const double sc = (double)g_f[t] / sqrt(var + EPSV);
        sb2[t] = (float)sc;
        sb2[64 + t] = (float)((double)b_f[t] - mu * sc);
    }
}

// ---------------- K7: final BN+leaky + transpose to [B,O,N] ----------------------
__global__ __launch_bounds__(256) void final_kernel(const float* __restrict__ f_buf,
                                                    const float* __restrict__ sb2,
                                                    float* __restrict__ out) {
    __shared__ float tile[64][65];
    const int sbid = ((blockIdx.x & 7) << 6) + (blockIdx.x >> 3);   // 1 batch/XCD
    const int b = sbid >> 6;                 // 512 blocks
    const int n0 = (sbid & 63) << 6;
#pragma unroll
    for (int r = 0; r < 16; ++r) {
        const int t = r * 256 + threadIdx.x;
        const int n = t >> 6, o = t & 63;
        const float v = f_buf[(size_t)((b << 12) + n0 + n) * 64 + o];
        const float h = fmaf(sb2[o], v, sb2[64 + o]);
        tile[n][o] = leaky(h);
    }
    __syncthreads();
#pragma unroll
    for (int r = 0; r < 16; ++r) {
        const int t = r * 256 + threadIdx.x;
        const int o = t >> 6, n = t & 63;
        out[(size_t)((b << 6) + o) * N_ + n0 + n] = tile[n][o];
    }
}

// ---------------- launch ---------------------------------------------------------
extern "C" void kernel_launch(void* const* d_in, const int* in_sizes, int n_in,
                              void* d_out, int out_size, void* d_ws, size_t ws_size,
                              hipStream_t stream) {
    (void)in_sizes; (void)n_in; (void)out_size; (void)ws_size;
    const float* x   = (const float*)d_in[0];
    const float* w_s = (const float*)d_in[1];
    const float* g_s = (const float*)d_in[2];
    const float* b_s = (const float*)d_in[3];
    const float* w_l = (const float*)d_in[4];
    const float* g_l = (const float*)d_in[5];
    const float* b_l = (const float*)d_in[6];
    const float* w_f = (const float*)d_in[7];
    const float* g_f = (const float*)d_in[8];
    const float* b_f = (const float*)d_in[9];
    float* out = (float*)d_out;
    char* ws = (char*)d_ws;

    constexpr size_t SZ_PT   = (size_t)B_ * N_ * 64 * 4;            // 8 MB
    constexpr size_t OFF_MXS = 0;
    constexpr size_t OFF_MNS = OFF_MXS + SZ_PT;
    constexpr size_t OFF_MXL = OFF_MNS + SZ_PT;
    constexpr size_t OFF_MNL = OFF_MXL + SZ_PT;
    constexpr size_t OFF_QST = OFF_MNL + SZ_PT;                     // 4 MB
    constexpr size_t OFF_PD1 = OFF_QST + (size_t)4096 * 256 * 4;
    constexpr size_t OFF_SB1 = OFF_PD1 + (size_t)32 * 256 * 8;
    constexpr size_t OFF_F   = OFF_SB1 + 1024;
    constexpr size_t OFF_P2  = OFF_F + SZ_PT;
    constexpr size_t OFF_PD2 = OFF_P2 + (size_t)2048 * 128 * 4;
    constexpr size_t OFF_SB2 = OFF_PD2 + (size_t)64 * 128 * 8;
    constexpr size_t OFF_SXP = OFF_SB2 + 1024;                      // 512 KB
    constexpr size_t OFF_PRM = OFF_SXP + (size_t)B_ * N_ * 16;      // 128 KB
    constexpr size_t OFF_CB  = OFF_PRM + (size_t)B_ * N_ * 4;       // 4 KB
    constexpr size_t OFF_XO4 = OFF_CB + (size_t)B_ * 64 * 8;        // 512 KB

    float*  mxs  = (float*)(ws + OFF_MXS);
    float*  mns  = (float*)(ws + OFF_MNS);
    float*  mxl  = (float*)(ws + OFF_MXL);
    float*  mnl  = (float*)(ws + OFF_MNL);
    float*  qst  = (float*)(ws + OFF_QST);
    double* pd1  = (double*)(ws + OFF_PD1);
    float*  sb1  = (float*)(ws + OFF_SB1);
    float*  fb   = (float*)(ws + OFF_F);
    float*  p2   = (float*)(ws + OFF_P2);
    double* pd2  = (double*)(ws + OFF_PD2);
    float*  sb2  = (float*)(ws + OFF_SB2);
    float4* sxp  = (float4*)(ws + OFF_SXP);
    int*    prm  = (int*)(ws + OFF_PRM);
    float2* cbv  = (float2*)(ws + OFF_CB);
    float4* xo4  = (float4*)(ws + OFF_XO4);

    hipLaunchKernelGGL(bucket_kernel, dim3(8), dim3(1024), 0, stream, x, sxp, prm, cbv, xo4);
    hipLaunchKernelGGL(knn_kernel, dim3(4096), dim3(256), 0, stream,
                       sxp, prm, cbv, xo4, w_s, w_l, mxs, mns, mxl, mnl, qst);
    hipLaunchKernelGGL(reduce1a_kernel, dim3(32), dim3(256), 0, stream, qst, pd1);
    hipLaunchKernelGGL(reduce1b_kernel, dim3(1), dim3(256), 0, stream, pd1, g_s, b_s, g_l, b_l, sb1);
    hipLaunchKernelGGL(fuse_kernel, dim3(2048), dim3(256), 0, stream,
                       mxs, mns, mxl, mnl, sb1, w_f, fb, p2);
    hipLaunchKernelGGL(reduce2a_kernel, dim3(64), dim3(128), 0, stream, p2, pd2);
    hipLaunchKernelGGL(reduce2b_kernel, dim3(1), dim3(128), 0, stream, pd2, g_f, b_f, sb2);
    hipLaunchKernelGGL(final_kernel, dim3(512), dim3(256), 0, stream, fb, sb2, out);
}

// Round 17
// 197.613 us; speedup vs baseline: 1.2188x; 1.0254x over previous
//
#include <hip/hip_runtime.h>

#define B_ 8
#define N_ 4096
#define O_ 64
#define KL 40
#define KS 20
#define EPSV 1e-5
#define SLOPE 0.2f

typedef unsigned long long u64;
typedef unsigned int u32;

__device__ __forceinline__ float leaky(float v) { return v >= 0.f ? v : SLOPE * v; }

// monotone float<->u32 maps (ascending float == ascending u32)
__device__ __forceinline__ u32 mfloat(float x) {
    const u32 u = __float_as_uint(x);
    return (u & 0x80000000u) ? ~u : (u | 0x80000000u);
}
__device__ __forceinline__ float unmfloat(u32 m) {
    return __uint_as_float((m & 0x80000000u) ? (m ^ 0x80000000u) : ~m);
}

// lane exchange by XOR stride S. S=1,2,8 via DPP (VALU, no LDS); S=4,16,32,63 via
// ds_bpermute with a HOISTED per-lane address.
template <int S>
__device__ __forceinline__ u64 xor_ex64(u64 v, int dsaddr) {
    if constexpr (S == 1 || S == 2 || S == 8) {
        constexpr int CTRL = (S == 1) ? 0xB1 : (S == 2) ? 0x4E : 0x128;
        const int lo = __builtin_amdgcn_update_dpp(0, (int)(u32)v, CTRL, 0xF, 0xF, true);
        const int hi = __builtin_amdgcn_update_dpp(0, (int)(u32)(v >> 32), CTRL, 0xF, 0xF, true);
        return ((u64)(u32)hi << 32) | (u32)lo;
    } else {
        const int lo = __builtin_amdgcn_ds_bpermute(dsaddr, (int)(u32)v);
        const int hi = __builtin_amdgcn_ds_bpermute(dsaddr, (int)(u32)(v >> 32));
        return ((u64)(u32)hi << 32) | (u32)lo;
    }
}

// one bitonic stage (level K, stride S) applied to two independent keys (ILP x2)
template <int K, int S>
__device__ __forceinline__ void stage_pair(u64& a, u64& e, int lane, int dsaddr) {
    const u64 oa = xor_ex64<S>(a, dsaddr);
    const u64 oe = xor_ex64<S>(e, dsaddr);
    const bool sel = (((lane & K) == 0) == ((lane & S) == 0));
    a = ((a < oa) == sel) ? a : oa;
    e = ((e < oe) == sel) ? e : oe;
}

// dual ascending bitonic sort of two independent 64-key sets
__device__ __forceinline__ void sort64_pair(u64& a, u64& e, int lane,
                                            int a4, int a16, int a32) {
    stage_pair<2, 1>(a, e, lane, 0);
    stage_pair<4, 2>(a, e, lane, 0);    stage_pair<4, 1>(a, e, lane, 0);
    stage_pair<8, 4>(a, e, lane, a4);   stage_pair<8, 2>(a, e, lane, 0);    stage_pair<8, 1>(a, e, lane, 0);
    stage_pair<16, 8>(a, e, lane, 0);   stage_pair<16, 4>(a, e, lane, a4);  stage_pair<16, 2>(a, e, lane, 0);   stage_pair<16, 1>(a, e, lane, 0);
    stage_pair<32, 16>(a, e, lane, a16); stage_pair<32, 8>(a, e, lane, 0);  stage_pair<32, 4>(a, e, lane, a4);  stage_pair<32, 2>(a, e, lane, 0);  stage_pair<32, 1>(a, e, lane, 0);
    stage_pair<64, 32>(a, e, lane, a32); stage_pair<64, 16>(a, e, lane, a16); stage_pair<64, 8>(a, e, lane, 0); stage_pair<64, 4>(a, e, lane, a4); stage_pair<64, 2>(a, e, lane, 0); stage_pair<64, 1>(a, e, lane, 0);
}

// L0/L1 ascending lists; a/e ascending buffers. keep 64 smallest of each union.
__device__ __forceinline__ void merge_pair(u64& L0, u64& L1, u64 a, u64 e, int lane,
                                           int a4, int a16, int a32, int a63) {
    const u64 ra = xor_ex64<63>(a, a63);         // reverse -> descending
    const u64 re = xor_ex64<63>(e, a63);
    L0 = (L0 < ra) ? L0 : ra;                    // valley min -> bitonic
    L1 = (L1 < re) ? L1 : re;
    stage_pair<0, 32>(L0, L1, lane, a32);        // K=0 -> pure descending cleanup
    stage_pair<0, 16>(L0, L1, lane, a16);
    stage_pair<0, 8>(L0, L1, lane, 0);
    stage_pair<0, 4>(L0, L1, lane, a4);
    stage_pair<0, 2>(L0, L1, lane, 0);
    stage_pair<0, 1>(L0, L1, lane, 0);
}

// ---------------- K0: bucket points by x -> packed array, envelopes, orig coords -
__global__ __launch_bounds__(1024) void bucket_kernel(const float* __restrict__ x,
                                                      float4* __restrict__ sxp,
                                                      int* __restrict__ perm,
                                                      float2* __restrict__ cb,
                                                      float4* __restrict__ xo4) {
    __shared__ int hist[256];
    __shared__ int scan[256];
    __shared__ int ofs[256];
    __shared__ u32 xsm[4096];
    __shared__ float redmin[16], redmax[16];
    __shared__ u32 wmin[64], wmax[64];
    __shared__ u32 wsuf[64], wpre[64];
    const int b = blockIdx.x;
    const float* xb = x + (size_t)b * 3 * N_;
    const int t = threadIdx.x;
    float xv[4];
    float mn = INFINITY, mx = -INFINITY;
#pragma unroll
    for (int p = 0; p < 4; ++p) {
        xv[p] = xb[t + p * 1024];
        mn = fminf(mn, xv[p]); mx = fmaxf(mx, xv[p]);
    }
#pragma unroll
    for (int s = 1; s < 64; s <<= 1) {
        mn = fminf(mn, __shfl_xor(mn, s));
        mx = fmaxf(mx, __shfl_xor(mx, s));
    }
    if ((t & 63) == 0) { redmin[t >> 6] = mn; redmax[t >> 6] = mx; }
    if (t < 256) hist[t] = 0;
    __syncthreads();
    if (t == 0) {
        float m0 = INFINITY, m1 = -INFINITY;
        for (int w = 0; w < 16; ++w) { m0 = fminf(m0, redmin[w]); m1 = fmaxf(m1, redmax[w]); }
        redmin[0] = m0; redmax[0] = m1;
    }
    __syncthreads();
    const float xmin = redmin[0];
    const float scale = 256.0f / fmaxf(redmax[0] - xmin, 1e-20f);
    int bk[4];
#pragma unroll
    for (int p = 0; p < 4; ++p) {
        bk[p] = min(255, max(0, (int)((xv[p] - xmin) * scale)));
        atomicAdd(&hist[bk[p]], 1);
    }
    __syncthreads();
    if (t < 256) scan[t] = hist[t];
    __syncthreads();
#pragma unroll
    for (int s = 1; s < 256; s <<= 1) {
        int v = 0;
        if (t < 256 && t >= s) v = scan[t - s];
        __syncthreads();
        if (t < 256) scan[t] += v;
        __syncthreads();
    }
    if (t < 256) ofs[t] = scan[t] - hist[t];
    if (t < 64) { wmin[t] = 0xFFFFFFFFu; wmax[t] = 0; }
    __syncthreads();
#pragma unroll
    for (int p = 0; p < 4; ++p) {
        const int i = t + p * 1024;
        const int dst = atomicAdd(&ofs[bk[p]], 1);
        const float cx = xv[p], cy = xb[N_ + i], cz = xb[2 * N_ + i];
        sxp[((size_t)b << 12) + dst] = make_float4(2.f * cx, 2.f * cy, 2.f * cz,
                                                   -(cx * cx + cy * cy + cz * cz));
        perm[(b << 12) + dst] = i;
        xo4[((size_t)b << 12) + i] = make_float4(cx, cy, cz, 0.f);
        xsm[dst] = mfloat(cx);
    }
    __syncthreads();
#pragma unroll
    for (int p = 0; p < 4; ++p) {
        const int pos = t + p * 1024;
        const int w = pos >> 6;
        atomicMin(&wmin[w], xsm[pos]);
        atomicMax(&wmax[w], xsm[pos]);
    }
    __syncthreads();
    // monotone envelopes in parallel: suffix-min of lows, prefix-max of highs
    if (t < 64) {
        u32 sm = 0xFFFFFFFFu;
        for (int w = t; w < 64; ++w) sm = min(sm, wmin[w]);
        wsuf[t] = sm;
    } else if (t < 128) {
        const int tt = t - 64;
        u32 pm2 = 0;
        for (int w = 0; w <= tt; ++w) pm2 = max(pm2, wmax[w]);
        wpre[tt] = pm2;
    }
    __syncthreads();
    if (t < 64) cb[(b << 6) + t] = make_float2(unmfloat(wsuf[t]), unmfloat(wpre[t]));
}

// ---------------- K1: KNN (home-init + pruned spiral) + fused edge-conv stats ----
__global__ __launch_bounds__(256, 8) void knn_kernel(const float4* __restrict__ sxp,
                                                     const int* __restrict__ perm,
                                                     const float2* __restrict__ cb,
                                                     const float4* __restrict__ xo4,
                                                     const float* __restrict__ w_s,
                                                     const float* __restrict__ w_l,
                                                     float* __restrict__ max_s,
                                                     float* __restrict__ min_s,
                                                     float* __restrict__ max_l,
                                                     float* __restrict__ min_l,
                                                     float* __restrict__ qstats) {
    __shared__ u64 buf[4][2][128];      // 8 KB candidate buffers
    __shared__ float2 cbl[64];          // window x-envelopes
    __shared__ float4 sbuf[4][2][KL];   // 5 KB: per-wave neighbor coords
    __shared__ float sred[4][4][64];    // 4 KB: per-wave stat partials
    const int sbid = ((blockIdx.x & 7) << 9) | (blockIdx.x >> 3);  // 1 batch/XCD
    const int b = sbid >> 9;
    const int qbase = (sbid & 511) << 3;     // 8 sorted-position queries per block
    const int tid = threadIdx.x;
    const int wave = tid >> 6, lane = tid & 63;
    if (tid < 64) cbl[tid] = cb[(b << 6) + tid];
    const int a4 = (lane ^ 4) << 2, a16 = (lane ^ 16) << 2;
    const int a32 = (lane ^ 32) << 2, a63 = (lane ^ 63) << 2;
    const float4* sp = sxp + ((size_t)b << 12);
    const int* pm = perm + (b << 12);
    const float4* xo = xo4 + ((size_t)b << 12);
    const int i0 = qbase + wave * 2;
    const float4 p0 = sp[i0], p1 = sp[i0 + 1];
    const float qx0 = 0.5f * p0.x, qy0 = 0.5f * p0.y, qz0 = 0.5f * p0.z, nw0 = p0.w;
    const float qx1 = 0.5f * p1.x, qy1 = 0.5f * p1.y, qz1 = 0.5f * p1.z, nw1 = p1.w;
    const float qxmin = fminf(qx0, qx1), qxmax = fmaxf(qx0, qx1);
    int cnt0 = 0, cnt1 = 0;
    __syncthreads();
    const int home = i0 >> 6;
    // ---- home-window direct-sort init: list = sorted home candidates ------------
    u64 L0, L1;
    float th0, th1;
    {
        const int js = (home << 6) + lane;
        const float4 ch = sp[js];
        const int pj = pm[js];
        const float d0 = fmaf(qx0, ch.x, fmaf(qy0, ch.y, fmaf(qz0, ch.z, ch.w + nw0)));
        const float d1 = fmaf(qx1, ch.x, fmaf(qy1, ch.y, fmaf(qz1, ch.z, ch.w + nw1)));
        u64 k0 = ((u64)__float_as_uint(fminf(d0, -0.0f)) << 32) | (u32)pj;
        u64 k1 = ((u64)__float_as_uint(fminf(d1, -0.0f)) << 32) | (u32)pj;
        sort64_pair(k0, k1, lane, a4, a16, a32);
        L0 = k0; L1 = k1;
        th0 = __uint_as_float((u32)__builtin_amdgcn_readlane((int)(u32)(L0 >> 32), KL - 1));
        th1 = __uint_as_float((u32)__builtin_amdgcn_readlane((int)(u32)(L1 >> 32), KL - 1));
    }
    // ---- pruned spiral over remaining windows, prefetch pipeline ----------------
    int cl = home - 1, cr = home + 1;
    bool openL = (cl >= 0), openR = (cr < 64);
    bool takeR = true;
    int c = -1;
    float4 cd = make_float4(0.f, 0.f, 0.f, 0.f);
    int pj = 0;
    for (;;) {           // pick first window
        if (!openL && !openR) break;
        const bool pickR = openR && (takeR || !openL);
        takeR = !pickR;
        const float r2 = -fminf(th0, th1);
        if (pickR) {
            const float dx = cbl[cr].x - qxmax;
            if (dx > 0.f && dx * dx > r2) { openR = false; continue; }
            c = cr++; if (cr >= 64) openR = false; break;
        } else {
            const float dx = qxmin - cbl[cl].y;
            if (dx > 0.f && dx * dx > r2) { openL = false; continue; }
            c = cl--; if (cl < 0) openL = false; break;
        }
    }
    if (c >= 0) { cd = sp[(c << 6) + lane]; pj = pm[(c << 6) + lane]; }
    while (c >= 0) {
        int cn = -1;     // pick next window + prefetch its data
        for (;;) {
            if (!openL && !openR) break;
            const bool pickR = openR && (takeR || !openL);
            takeR = !pickR;
            const float r2 = -fminf(th0, th1);
            if (pickR) {
                const float dx = cbl[cr].x - qxmax;
                if (dx > 0.f && dx * dx > r2) { openR = false; continue; }
                cn = cr++; if (cr >= 64) openR = false; break;
            } else {
                const float dx = qxmin - cbl[cl].y;
                if (dx > 0.f && dx * dx > r2) { openL = false; continue; }
                cn = cl--; if (cl < 0) openL = false; break;
            }
        }
        float4 nd = make_float4(0.f, 0.f, 0.f, 0.f);
        int nj = 0;
        if (cn >= 0) { nd = sp[(cn << 6) + lane]; nj = pm[(cn << 6) + lane]; }
        // scan current window
        {
            const float d0 = fmaf(qx0, cd.x, fmaf(qy0, cd.y, fmaf(qz0, cd.z, cd.w + nw0)));
            const float d1 = fmaf(qx1, cd.x, fmaf(qy1, cd.y, fmaf(qz1, cd.z, cd.w + nw1)));
            const bool pr0 = (d0 >= th0), pr1 = (d1 >= th1);
            const u64 m0 = __ballot(pr0), m1 = __ballot(pr1);
            if (m0) {
                const int pos = cnt0 + __builtin_amdgcn_mbcnt_hi(
                    (u32)(m0 >> 32), __builtin_amdgcn_mbcnt_lo((u32)m0, 0));
                if (pr0) {
                    const u32 kd = __float_as_uint(fminf(d0, -0.0f));
                    buf[wave][0][pos] = ((u64)kd << 32) | (u32)pj;
                }
                cnt0 += __popcll(m0);
            }
            if (m1) {
                const int pos = cnt1 + __builtin_amdgcn_mbcnt_hi(
                    (u32)(m1 >> 32), __builtin_amdgcn_mbcnt_lo((u32)m1, 0));
                if (pr1) {
                    const u32 kd = __float_as_uint(fminf(d1, -0.0f));
                    buf[wave][1][pos] = ((u64)kd << 32) | (u32)pj;
                }
                cnt1 += __popcll(m1);
            }
            if ((cnt0 | cnt1) >= 64) {
                const int t0 = min(cnt0, 64), t1 = min(cnt1, 64);
                u64 a = (lane < t0) ? buf[wave][0][cnt0 - t0 + lane] : ~0ull;
                u64 e = (lane < t1) ? buf[wave][1][cnt1 - t1 + lane] : ~0ull;
                sort64_pair(a, e, lane, a4, a16, a32);
                merge_pair(L0, L1, a, e, lane, a4, a16, a32, a63);
                th0 = __uint_as_float((u32)__builtin_amdgcn_readlane((int)(u32)(L0 >> 32), KL - 1));
                th1 = __uint_as_float((u32)__builtin_amdgcn_readlane((int)(u32)(L1 >> 32), KL - 1));
                cnt0 -= t0; cnt1 -= t1;
            }
        }
        c = cn; cd = nd; pj = nj;
    }
    if ((cnt0 | cnt1) > 0) {                  // leftovers (< 64 each)
        u64 a = (lane < cnt0) ? buf[wave][0][lane] : ~0ull;
        u64 e = (lane < cnt1) ? buf[wave][1][lane] : ~0ull;
        sort64_pair(a, e, lane, a4, a16, a32);
        merge_pair(L0, L1, a, e, lane, a4, a16, a32, a63);
    }
    // ---- fused edge-conv stats epilogue ------------------------------------------
    if (lane < KL) {
        sbuf[wave][0][lane] = xo[(int)((u32)L0 & 4095u)];
        sbuf[wave][1][lane] = xo[(int)((u32)L1 & 4095u)];
    }
    __builtin_amdgcn_wave_barrier();     // per-wave LDS RAW; DS pipe is in-order
    const int lw = lane * 6;             // lane = output channel
    const float ws0 = w_s[lw], ws1 = w_s[lw + 1], ws2 = w_s[lw + 2];
    const float ds0 = w_s[lw + 3] - ws0, ds1 = w_s[lw + 4] - ws1, ds2 = w_s[lw + 5] - ws2;
    const float wl0 = w_l[lw], wl1 = w_l[lw + 1], wl2 = w_l[lw + 2];
    const float dl0 = w_l[lw + 3] - wl0, dl1 = w_l[lw + 4] - wl1, dl2 = w_l[lw + 5] - wl2;
    const int oi0 = pm[i0], oi1 = pm[i0 + 1];
    float st[4] = {0.f, 0.f, 0.f, 0.f};  // sums, sss, suml, ssl (both queries)
#pragma unroll
    for (int q = 0; q < 2; ++q) {
        const float qx = q ? qx1 : qx0, qy = q ? qy1 : qy0, qz = q ? qz1 : qz0;
        const int oi = q ? oi1 : oi0;
        const float cs = fmaf(ds0, qx, fmaf(ds1, qy, ds2 * qz));
        const float cq = fmaf(dl0, qx, fmaf(dl1, qy, dl2 * qz));
        float mxs = -INFINITY, mns = INFINITY, mxl = -INFINITY, mnl = INFINITY;
        float sums = 0.f, sss = 0.f, suml = 0.f, ssl = 0.f;
#pragma unroll
        for (int k = 0; k < KL; ++k) {
            const float4 xj = sbuf[wave][q][k];          // LDS broadcast
            const float hl = fmaf(wl0, xj.x, fmaf(wl1, xj.y, fmaf(wl2, xj.z, cq)));
            mxl = fmaxf(mxl, hl); mnl = fminf(mnl, hl);
            suml += hl; ssl = fmaf(hl, hl, ssl);
            if (k < KS) {
                const float hs = fmaf(ws0, xj.x, fmaf(ws1, xj.y, fmaf(ws2, xj.z, cs)));
                mxs = fmaxf(mxs, hs); mns = fminf(mns, hs);
                sums += hs; sss = fmaf(hs, hs, sss);
            }
        }
        const size_t base = (size_t)((b << 12) + oi) * 64 + lane;
        max_s[base] = mxs; min_s[base] = mns;
        max_l[base] = mxl; min_l[base] = mnl;
        st[0] += sums; st[1] += sss; st[2] += suml; st[3] += ssl;
    }
#pragma unroll
    for (int s = 0; s < 4; ++s) sred[wave][s][lane] = st[s];
    __syncthreads();
    if (tid < 256) {
        const int s = tid >> 6, ch = tid & 63;
        qstats[(size_t)blockIdx.x * 256 + tid] =
            sred[0][s][ch] + sred[1][s][ch] + sred[2][s][ch] + sred[3][s][ch];
    }
}

// ---------------- K4a/K4b: reduce edge-conv BN stats -> scale/bias ---------------
__global__ void reduce1a_kernel(const float* __restrict__ qstats, double* __restrict__ partialD1) {
    const int t = threadIdx.x;   // 256, 32 blocks
    double acc = 0.0;
    const int r0 = blockIdx.x * 128;
    for (int r = 0; r < 128; ++r) acc += (double)qstats[(size_t)(r0 + r) * 256 + t];
    partialD1[(size_t)blockIdx.x * 256 + t] = acc;
}

__global__ void reduce1b_kernel(const double* __restrict__ partialD1,
                                const float* __restrict__ g_s, const float* __restrict__ b_s,
                                const float* __restrict__ g_l, const float* __restrict__ b_l,
                                float* __restrict__ sb1) {
    const int t = threadIdx.x;   // 256
    double acc = 0.0;
    for (int r = 0; r < 32; ++r) acc += partialD1[(size_t)r * 256 + t];
    __shared__ double sums[256];
    sums[t] = acc;
    __syncthreads();
    if (t < 64) {
        const double ns = (double)B_ * N_ * KS;
        const double nl = (double)B_ * N_ * KL;
        double mu = sums[t] / ns;
        double var = sums[64 + t] / ns - mu * mu;
        double sc = (double)g_s[t] / sqrt(var + EPSV);
        sb1[t] = (float)sc;
        sb1[64 + t] = (float)((double)b_s[t] - mu * sc);
        mu = sums[128 + t] / nl;
        var = sums[192 + t] / nl - mu * mu;
        sc = (double)g_l[t] / sqrt(var + EPSV);
        sb1[128 + t] = (float)sc;
        sb1[192 + t] = (float)((double)b_l[t] - mu * sc);
    }
}

// ---------------- K5: BN+leaky on maxes, 64x128 fuse matvec, stats ---------------
__global__ __launch_bounds__(256) void fuse_kernel(
    const float* __restrict__ max_s, const float* __restrict__ min_s,
    const float* __restrict__ max_l, const float* __restrict__ min_l,
    const float* __restrict__ sb1, const float* __restrict__ w_f,
    float* __restrict__ f_buf, float* __restrict__ partial2) {
    __shared__ float wfT[128 * 64];   // transposed: wfT[c][o]
    __shared__ float av[4][128];
    __shared__ float red[2][4][64];
    const int tid = threadIdx.x;
    for (int t = tid; t < 8192; t += 256) {
        const int c = t >> 6, o = t & 63;
        wfT[t] = w_f[o * 128 + c];
    }
    const int sbid = ((blockIdx.x & 7) << 8) + (blockIdx.x >> 3);   // 1 batch/XCD
    const int wave = tid >> 6, lane = tid & 63;
    const float sc_s = sb1[lane], bi_s = sb1[64 + lane];
    const float sc_l = sb1[128 + lane], bi_l = sb1[192 + lane];
    float sum_f = 0.f, ss_f = 0.f;
    __syncthreads();
    for (int p = 0; p < 4; ++p) {
        const int bn = (sbid * 4 + wave) * 4 + p;   // 2048 blocks
        const size_t base = (size_t)bn * 64 + lane;
        const float hs = sc_s >= 0.f ? max_s[base] : min_s[base];
        const float a_s = leaky(fmaf(sc_s, hs, bi_s));
        const float hl = sc_l >= 0.f ? max_l[base] : min_l[base];
        const float a_l = leaky(fmaf(sc_l, hl, bi_l));
        av[wave][lane] = a_s;
        av[wave][64 + lane] = a_l;     // per-wave buffer: no block barrier needed
        float acc = 0.f;
#pragma unroll
        for (int c = 0; c < 128; ++c) acc = fmaf(wfT[c * 64 + lane], av[wave][c], acc);
        f_buf[base] = acc;
        sum_f += acc;
        ss_f = fmaf(acc, acc, ss_f);
    }
    red[0][wave][lane] = sum_f;
    red[1][wave][lane] = ss_f;
    __syncthreads();
    if (tid < 128) {
        const int st = tid >> 6, o = tid & 63;
        partial2[(size_t)blockIdx.x * 128 + tid] =
            red[st][0][o] + red[st][1][o] + red[st][2][o] + red[st][3][o];
    }
}

// ---------------- K6a/K6b: reduce final BN stats ---------------------------------
__global__ void reduce2a_kernel(const float* __restrict__ partial2, double* __restrict__ partialD2) {
    const int t = threadIdx.x;   // 128
    double acc = 0.0;
    const int r0 = blockIdx.x * 32;   // 64 blocks
    for (int r = 0; r < 32; ++r) acc += (double)partial2[(size_t)(r0 + r) * 128 + t];
    partialD2[(size_t)blockIdx.x * 128 + t] = acc;
}

__global__ void reduce2b_kernel(const double* __restrict__ partialD2,
                                const float* __restrict__ g_f, const float* __restrict__ b_f,
                                float* __restrict__ sb2) {
    const int t = threadIdx.x;   // 128
    double acc = 0.0;
    for (int r = 0; r < 64; ++r) acc += partialD2[(size_t)r * 128 + t];
    __shared__ double sums[128];
    sums[t] = acc;
    __syncthreads();
    if (t < 64) {
        const double n = (double)B_ * N_;
        const double mu = sums[t] / n;
        const double var = sums[64 + t] / n - mu * mu;
        const double sc = (double)g_f[t] / sqrt(var + EPSV);
        sb2[t] = (float)sc;
        sb2[64 + t] = (float)((double)b_f[t] - mu * sc);
    }
}

// ---------------- K7: final BN+leaky + transpose to [B,O,N] ----------------------
__global__ __launch_bounds__(256) void final_kernel(const float* __restrict__ f_buf,
                                                    const float* __restrict__ sb2,
                                                    float* __restrict__ out) {
    __shared__ float tile[64][65];
    const int sbid = ((blockIdx.x & 7) << 6) + (blockIdx.x >> 3);   // 1 batch/XCD
    const int b = sbid >> 6;                 // 512 blocks
    const int n0 = (sbid & 63) << 6;
#pragma unroll
    for (int r = 0; r < 16; ++r) {
        const int t = r * 256 + threadIdx.x;
        const int n = t >> 6, o = t & 63;
        const float v = f_buf[(size_t)((b << 12) + n0 + n) * 64 + o];
        const float h = fmaf(sb2[o], v, sb2[64 + o]);
        tile[n][o] = leaky(h);
    }
    __syncthreads();
#pragma unroll
    for (int r = 0; r < 16; ++r) {
        const int t = r * 256 + threadIdx.x;
        const int o = t >> 6, n = t & 63;
        out[(size_t)((b << 6) + o) * N_ + n0 + n] = tile[n][o];
    }
}

// ---------------- launch ---------------------------------------------------------
extern "C" void kernel_launch(void* const* d_in, const int* in_sizes, int n_in,
                              void* d_out, int out_size, void* d_ws, size_t ws_size,
                              hipStream_t stream) {
    (void)in_sizes; (void)n_in; (void)out_size; (void)ws_size;
    const float* x   = (const float*)d_in[0];
    const float* w_s = (const float*)d_in[1];
    const float* g_s = (const float*)d_in[2];
    const float* b_s = (const float*)d_in[3];
    const float* w_l = (const float*)d_in[4];
    const float* g_l = (const float*)d_in[5];
    const float* b_l = (const float*)d_in[6];
    const float* w_f = (const float*)d_in[7];
    const float* g_f = (const float*)d_in[8];
    const float* b_f = (const float*)d_in[9];
    float* out = (float*)d_out;
    char* ws = (char*)d_ws;

    constexpr size_t SZ_PT   = (size_t)B_ * N_ * 64 * 4;            // 8 MB
    constexpr size_t OFF_MXS = 0;
    constexpr size_t OFF_MNS = OFF_MXS + SZ_PT;
    constexpr size_t OFF_MXL = OFF_MNS + SZ_PT;
    constexpr size_t OFF_MNL = OFF_MXL + SZ_PT;
    constexpr size_t OFF_QST = OFF_MNL + SZ_PT;                     // 4 MB
    constexpr size_t OFF_PD1 = OFF_QST + (size_t)4096 * 256 * 4;
    constexpr size_t OFF_SB1 = OFF_PD1 + (size_t)32 * 256 * 8;
    constexpr size_t OFF_F   = OFF_SB1 + 1024;
    constexpr size_t OFF_P2  = OFF_F + SZ_PT;
    constexpr size_t OFF_PD2 = OFF_P2 + (size_t)2048 * 128 * 4;
    constexpr size_t OFF_SB2 = OFF_PD2 + (size_t)64 * 128 * 8;
    constexpr size_t OFF_SXP = OFF_SB2 + 1024;                      // 512 KB
    constexpr size_t OFF_PRM = OFF_SXP + (size_t)B_ * N_ * 16;      // 128 KB
    constexpr size_t OFF_CB  = OFF_PRM + (size_t)B_ * N_ * 4;       // 4 KB
    constexpr size_t OFF_XO4 = OFF_CB + (size_t)B_ * 64 * 8;        // 512 KB

    float*  mxs  = (float*)(ws + OFF_MXS);
    float*  mns  = (float*)(ws + OFF_MNS);
    float*  mxl  = (float*)(ws + OFF_MXL);
    float*  mnl  = (float*)(ws + OFF_MNL);
    float*  qst  = (float*)(ws + OFF_QST);
    double* pd1  = (double*)(ws + OFF_PD1);
    float*  sb1  = (float*)(ws + OFF_SB1);
    float*  fb   = (float*)(ws + OFF_F);
    float*  p2   = (float*)(ws + OFF_P2);
    double* pd2  = (double*)(ws + OFF_PD2);
    float*  sb2  = (float*)(ws + OFF_SB2);
    float4* sxp  = (float4*)(ws + OFF_SXP);
    int*    prm  = (int*)(ws + OFF_PRM);
    float2* cbv  = (float2*)(ws + OFF_CB);
    float4* xo4  = (float4*)(ws + OFF_XO4);

    hipLaunchKernelGGL(bucket_kernel, dim3(8), dim3(1024), 0, stream, x, sxp, prm, cbv, xo4);
    hipLaunchKernelGGL(knn_kernel, dim3(4096), dim3(256), 0, stream,
                       sxp, prm, cbv, xo4, w_s, w_l, mxs, mns, mxl, mnl, qst);
    hipLaunchKernelGGL(reduce1a_kernel, dim3(32), dim3(256), 0, stream, qst, pd1);
    hipLaunchKernelGGL(reduce1b_kernel, dim3(1), dim3(256), 0, stream, pd1, g_s, b_s, g_l, b_l, sb1);
    hipLaunchKernelGGL(fuse_kernel, dim3(2048), dim3(256), 0, stream,
                       mxs, mns, mxl, mnl, sb1, w_f, fb, p2);
    hipLaunchKernelGGL(reduce2a_kernel, dim3(64), dim3(128), 0, stream, p2, pd2);
    hipLaunchKernelGGL(reduce2b_kernel, dim3(1), dim3(128), 0, stream, pd2, g_f, b_f, sb2);
    hipLaunchKernelGGL(final_kernel, dim3(512), dim3(256), 0, stream, fb, sb2, out);
}